// Round 11
// baseline (24.056 us; speedup 1.0000x reference)
//
#include <hip/hip_runtime.h>
#include <math.h>

typedef __attribute__((ext_vector_type(4))) float f32x4;

__device__ __forceinline__ float rcpf(float x){ return __builtin_amdgcn_rcpf(x); }

__global__ __launch_bounds__(1024, 4) void phys11(
    const float* __restrict__ x,
    const float* __restrict__ W1, const float* __restrict__ b1,
    const float* __restrict__ W2, const float* __restrict__ b2,
    const float* __restrict__ W3, const float* __restrict__ b3,
    const float* __restrict__ W4, const float* __restrict__ b4,
    const float* __restrict__ i0p, const float* __restrict__ alphap,
    float* __restrict__ out, int nrows)
{
    __shared__ float hb[64*64];                 // [k][row] transposed hidden vector
    __shared__ __align__(16) float tab4[4000];  // [v][4] invbase per species
    __shared__ float latb[64*8];                // [row][lat0..5, x3, -]
    __shared__ float w4t[6*64];                 // [col][k] transposed W4

    const int tid  = threadIdx.x;
    const int lane = tid & 63;                                  // row within block
    const int wvu  = __builtin_amdgcn_readfirstlane(tid >> 6);  // wave id 0..15 (uniform)
    const int c0u  = 4*wvu;                                     // 4-column slice base

    // laundered copy of the column base: VGPR-resident, not provably uniform,
    // so weight loads become VMEM (vmcnt-ordered, deep-pipelined) instead of
    // chunk-serialized s_load/lgkmcnt(0).
    int c0v; asm("v_mov_b32 %0, %1" : "=v"(c0v) : "s"(c0u));

    // ---------------- prologue: voltage table + W4 transpose ----------------
    {
        const float KFRT = (float)(96485.33/(8.314*298.15));
        const float dV = 1.25f/999.0f;
        float a0=alphap[0], a1=alphap[1], a2=alphap[2];
        float i00=i0p[0], i01=i0p[1], i02=i0p[2];
        for (int v = tid; v < 1000; v += 1024){
            float Vv = -1.25f + (float)v*dV;
            tab4[v*4+0] = expf(a0*KFRT*(Vv+0.11f))/i00;
            tab4[v*4+1] = expf(a1*KFRT*(Vv-0.08f))/i01;
            tab4[v*4+2] = expf(a2*KFRT*(Vv))/i02;
            tab4[v*4+3] = 0.f;
        }
        if (tid < 384){ int k = tid/6, c = tid%6; w4t[c*64+k] = W4[tid]; }
    }

    // ---------------- MLP phase: lane = row, wave = 4-col slice ----------------
    const int rowg = blockIdx.x*64 + lane;
    const int rowc = min(rowg, nrows-1);
    float xv[5];
#pragma unroll
    for (int i=0;i<5;i++) xv[i] = x[rowc*5+i];
    if (wvu == 6) latb[lane*8+6] = xv[3];       // stash x3 for search phase

    // L1: exact nested-fmaf order; small weights via scalar path (one chunk)
    float hs[4];
#pragma unroll
    for (int j=0;j<4;j++){
        int c = c0u + j;
        float hv = b1[c];
        hv = fmaf(xv[0], W1[0*64+c], hv);
        hv = fmaf(xv[1], W1[1*64+c], hv);
        hv = fmaf(xv[2], W1[2*64+c], hv);
        hv = fmaf(xv[3], W1[3*64+c], hv);
        hv = fmaf(xv[4], W1[4*64+c], hv);
        hs[j] = fmaxf(hv, 0.f);
    }

    // 64->64 layer: weights via VMEM uniform loads, 8-k windows, double-buffered
    // (all buffer indices static after unroll); h per-k from LDS, interleaved.
    // Summation order identical to R7: A[k&3][j], k ascending, (A0+A1)+(A2+A3).
#define BIGLAYER(W, B)                                                        \
    {                                                                         \
        const float* Wp = (W) + c0v;                                          \
        float A[4][4];                                                        \
        _Pragma("unroll")                                                     \
        for (int j=0;j<4;j++){ A[0][j]=(B)[c0u+j]; A[1][j]=0.f; A[2][j]=0.f; A[3][j]=0.f; } \
        f32x4 wA[8], wB[8];                                                   \
        _Pragma("unroll")                                                     \
        for (int i=0;i<8;i++) wA[i] = *(const f32x4*)&Wp[i*64];               \
        _Pragma("unroll")                                                     \
        for (int w=0; w<8; w++){                                              \
            _Pragma("unroll")                                                 \
            for (int i=0;i<8;i++){                                            \
                if (w+1 < 8){                                                 \
                    f32x4 t = *(const f32x4*)&Wp[((w+1)*8+i)*64];             \
                    if (w & 1) wA[i] = t; else wB[i] = t;                     \
                }                                                             \
            }                                                                 \
            _Pragma("unroll")                                                 \
            for (int i=0;i<8;i++){                                            \
                const int k = w*8 + i;                                        \
                float hk = hb[k*64 + lane];                                   \
                f32x4 ww = (w & 1) ? wB[i] : wA[i];                           \
                A[i&3][0] = fmaf(hk, ww[0], A[i&3][0]);                       \
                A[i&3][1] = fmaf(hk, ww[1], A[i&3][1]);                       \
                A[i&3][2] = fmaf(hk, ww[2], A[i&3][2]);                       \
                A[i&3][3] = fmaf(hk, ww[3], A[i&3][3]);                       \
            }                                                                 \
        }                                                                     \
        _Pragma("unroll")                                                     \
        for (int j=0;j<4;j++) hs[j] = fmaxf((A[0][j]+A[1][j])+(A[2][j]+A[3][j]), 0.f); \
    }

    // publish h1 (transposed)
#pragma unroll
    for (int j=0;j<4;j++) hb[(c0u+j)*64 + lane] = hs[j];
    __syncthreads();

    BIGLAYER(W2, b2);          // h2 slice
    __syncthreads();           // all waves done reading h1
#pragma unroll
    for (int j=0;j<4;j++) hb[(c0u+j)*64 + lane] = hs[j];
    __syncthreads();

    BIGLAYER(W3, b3);          // h3 slice
    __syncthreads();           // all waves done reading h2
#pragma unroll
    for (int j=0;j<4;j++) hb[(c0u+j)*64 + lane] = hs[j];
    __syncthreads();

    // L4: waves 0..5, col = wvu; weights wave-uniform from w4t (LDS broadcast),
    // serial-chain order identical to prior rounds.
    if (wvu < 6){
        float a = b4[wvu];
#pragma unroll
        for (int k=0;k<64;k++)
            a = fmaf(hb[k*64 + lane], w4t[wvu*64 + k], a);
        latb[lane*8+wvu] = a;
    }
    __syncthreads();

    // ---------------- search phase: 8 threads per row (waves 0..7) ----------------
    if (tid >= 512) return;    // no barriers below

    const int row = tid >> 3;        // 0..63
    const int cg  = tid & 7;
    const int rw  = (tid >> 3) & 7;  // row-group within wave
    const int rowg2 = blockIdx.x*64 + row;

    const float lat0=latb[row*8+0], lat1=latb[row*8+1], lat2=latb[row*8+2];
    const float lat3=latb[row*8+3], lat4=latb[row*8+4], lat5=latb[row*8+5];
    const float x3 = latb[row*8+6];

    float rr   = 4e-8f * __expf(lat0);
    float epsv = rcpf(1.0f + __expf(-lat1));
    float Kdl  = __expf(lat2);
    float Deff = 1.91e-9f * epsv * sqrtf(epsv);
    float Kgdl = Kdl * Deff * rcpf(rr);
    float S    = rcpf(Kgdl) + fabsf(x3) * rcpf((1.0f - epsv) * Deff);
    float il0  = S * (float)(1.0 / (2.0  * 96485.33 * 34.0));
    float il1  = S * (float)(1.0 / (12.0 * 96485.33 * 34.0));

    float t0s = 2.0f*lat3, t1s = 2.0f*lat4, t2s = 2.0f*lat5;
    float mx = fmaxf(t0s, fmaxf(t1s, t2s));
    float e0 = __expf(t0s-mx), e1 = __expf(t1s-mx), e2 = __expf(t2s-mx);
    float se = e0 + e1 + e2;
    float it0 = se*rcpf(e0), it1 = se*rcpf(e1), it2 = se*rcpf(e2);

    auto itot = [&](int v) -> float {
        f32x4 tb = *(const f32x4*)&tab4[v*4];
        return rcpf(fmaf(tb.x, it0, il0)) + rcpf(fmaf(tb.y, it1, il1)) + rcpf(tb.z*it2);
    };

    // i_tot strictly decreasing in v (2%/step >> float noise).
    bool le0f = itot(0)   <= 200.0f;
    bool le9f = itot(999) <= 200.0f;

    int lo = 0, hi = 999;
#pragma unroll 1
    for (int rd = 0; rd < 3; ++rd){
        int L = hi - lo;
        int p = lo + (L*(cg+1))/9;
        bool le = itot(p) <= 200.0f;
        unsigned long long bal = __ballot(le);
        unsigned m8 = (unsigned)((bal >> (8*rw)) & 0xFFull);
        int tz  = (m8 == 0u) ? 8 : (int)__builtin_ctz(m8);
        int nlo = (tz > 0) ? lo + (L*tz)/9 : lo;
        int nhi = (tz < 8) ? lo + (L*(tz+1))/9 : hi;
        lo = nlo; hi = nhi;
    }
    // interval now <= 2 wide; one unconditional bisect step (no-op at width 1)
    {
        int mid = lo + ((hi-lo)>>1);
        bool lem = itot(mid) <= 200.0f;
        hi = lem ? mid : hi;
        lo = lem ? lo  : mid;
    }
    float da = itot(lo) - 200.0f;   // > 0 under invariant
    float db = 200.0f - itot(hi);   // >= 0
    int idx = (da <= db) ? lo : hi; // tie -> earlier index (argmin-first)
    if (!le9f) idx = 999;
    if (le0f)  idx = 0;

    f32x4 tb = *(const f32x4*)&tab4[idx*4];
    float s0 = rcpf(fmaf(tb.x, it0, il0));
    float s1 = rcpf(fmaf(tb.y, it1, il1));
    float s2 = rcpf(tb.z*it2);
    float inv = rcpf(s0 + s1 + s2);

    if (cg == 0 && rowg2 < nrows){
        float2 o; o.x = s1*inv; o.y = s0*inv;
        reinterpret_cast<float2*>(out)[rowg2] = o;
    }
}

extern "C" void kernel_launch(void* const* d_in, const int* in_sizes, int n_in,
                              void* d_out, int out_size, void* d_ws, size_t ws_size,
                              hipStream_t stream) {
    (void)n_in; (void)d_ws; (void)ws_size; (void)out_size;
    int nrows = in_sizes[0] / 5;
    int nblk = (nrows + 63) / 64;
    phys11<<<dim3(nblk), dim3(1024), 0, stream>>>(
        (const float*)d_in[0],
        (const float*)d_in[1], (const float*)d_in[2],
        (const float*)d_in[3], (const float*)d_in[4],
        (const float*)d_in[5], (const float*)d_in[6],
        (const float*)d_in[7], (const float*)d_in[8],
        (const float*)d_in[9], (const float*)d_in[10],
        (float*)d_out, nrows);
}

// Round 12
// 19.472 us; speedup vs baseline: 1.2354x; 1.2354x over previous
//
#include <hip/hip_runtime.h>
#include <math.h>

typedef __attribute__((ext_vector_type(4))) float f32x4;

__device__ __forceinline__ float rcpf(float x){ return __builtin_amdgcn_rcpf(x); }

// swizzled 16B-slot index for [row][slot] LDS tile: involution slot ^= (row&7)
__device__ __forceinline__ int slotaddr(int r, int s){ return r*16 + (s ^ (r & 7)); }

__global__ __launch_bounds__(1024, 4) void phys12(
    const float* __restrict__ x,
    const float* __restrict__ W1, const float* __restrict__ b1,
    const float* __restrict__ W2, const float* __restrict__ b2,
    const float* __restrict__ W3, const float* __restrict__ b3,
    const float* __restrict__ W4, const float* __restrict__ b4,
    const float* __restrict__ i0p, const float* __restrict__ alphap,
    float* __restrict__ out, int nrows)
{
    __shared__ __align__(16) f32x4 hb[64*16];    // swizzled [row][slot], 16 KB
    __shared__ __align__(16) float tab4[4000];   // [v][4] invbase per species
    __shared__ float latb[64*8];                 // [row][lat0..5, x3, -]

    const int tid  = threadIdx.x;
    const int lane = tid & 63;                                  // row within block
    const int wvu  = __builtin_amdgcn_readfirstlane(tid >> 6);  // wave 0..15 (uniform)
    const int c0u  = 4*wvu;                                     // 4-col slice base

    // ---------------- prologue: voltage table ----------------
    {
        const float KFRT = (float)(96485.33/(8.314*298.15));
        const float dV = 1.25f/999.0f;
        float a0=alphap[0], a1=alphap[1], a2=alphap[2];
        float i00=i0p[0], i01=i0p[1], i02=i0p[2];
        for (int v = tid; v < 1000; v += 1024){
            float Vv = -1.25f + (float)v*dV;
            tab4[v*4+0] = expf(a0*KFRT*(Vv+0.11f))/i00;
            tab4[v*4+1] = expf(a1*KFRT*(Vv-0.08f))/i01;
            tab4[v*4+2] = expf(a2*KFRT*(Vv))/i02;
            tab4[v*4+3] = 0.f;
        }
    }

    // ---------------- MLP phase: lane = row, wave = 4-col slice ----------------
    const int rowg = blockIdx.x*64 + lane;
    const int rowc = min(rowg, nrows-1);
    float xv[5];
#pragma unroll
    for (int i=0;i<5;i++) xv[i] = x[rowc*5+i];
    if (wvu == 6) latb[lane*8+6] = xv[3];       // stash x3 for search phase

    // L1: exact nested-fmaf order (validated); weights via scalar path
    float hs[4];
#pragma unroll
    for (int j=0;j<4;j++){
        int c = c0u + j;
        float hv = b1[c];
        hv = fmaf(xv[0], W1[0*64+c], hv);
        hv = fmaf(xv[1], W1[1*64+c], hv);
        hv = fmaf(xv[2], W1[2*64+c], hv);
        hv = fmaf(xv[3], W1[3*64+c], hv);
        hv = fmaf(xv[4], W1[4*64+c], hv);
        hs[j] = fmaxf(hv, 0.f);
    }

    f32x4 hq[16];    // full hidden row in registers (all indices static)

#define PUBLISH()                                                         \
    {                                                                     \
        f32x4 t; t.x=hs[0]; t.y=hs[1]; t.z=hs[2]; t.w=hs[3];              \
        hb[slotaddr(lane, wvu)] = t;                                      \
    }

#define CONSUME()                                                         \
    {                                                                     \
        _Pragma("unroll")                                                 \
        for (int q=0;q<16;q++) hq[q] = hb[slotaddr(lane, q)];             \
    }

    // 64->64 layer: R7-exact A[k&3] rotation (k=4q+e ascending, k&3=e),
    // weights wave-uniform scalar loads, h from registers.
#define BIGLAYER(W, B)                                                    \
    {                                                                     \
        float A[4][4];                                                    \
        _Pragma("unroll")                                                 \
        for (int j=0;j<4;j++){ A[0][j]=(B)[c0u+j]; A[1][j]=0.f; A[2][j]=0.f; A[3][j]=0.f; } \
        _Pragma("unroll")                                                 \
        for (int q=0;q<16;q++){                                           \
            _Pragma("unroll")                                             \
            for (int e=0;e<4;e++){                                        \
                const int k = 4*q + e;                                    \
                float hk = hq[q][e];                                      \
                A[e][0] = fmaf(hk, (W)[k*64 + c0u + 0], A[e][0]);         \
                A[e][1] = fmaf(hk, (W)[k*64 + c0u + 1], A[e][1]);         \
                A[e][2] = fmaf(hk, (W)[k*64 + c0u + 2], A[e][2]);         \
                A[e][3] = fmaf(hk, (W)[k*64 + c0u + 3], A[e][3]);         \
            }                                                             \
        }                                                                 \
        _Pragma("unroll")                                                 \
        for (int j=0;j<4;j++) hs[j] = fmaxf((A[0][j]+A[1][j])+(A[2][j]+A[3][j]), 0.f); \
    }

    PUBLISH();                 // h1
    __syncthreads();
    CONSUME();
    __syncthreads();           // all waves consumed h1; hb free for h2
    BIGLAYER(W2, b2);
    PUBLISH();                 // h2
    __syncthreads();
    CONSUME();
    __syncthreads();           // all waves consumed h2; hb free for h3
    BIGLAYER(W3, b3);
    PUBLISH();                 // h3
    __syncthreads();

    // L4: waves 0..5, col = wvu; consume h3 into regs, serial chain (R8-validated
    // order: bias first, k ascending), weights via scalar loads.
    if (wvu < 6){
        CONSUME();
        float a = b4[wvu];
#pragma unroll
        for (int q=0;q<16;q++){
#pragma unroll
            for (int e=0;e<4;e++)
                a = fmaf(hq[q][e], W4[(4*q+e)*6 + wvu], a);
        }
        latb[lane*8+wvu] = a;
    }
    __syncthreads();

    // ---------------- search phase: 8 threads per row (waves 0..7) ----------------
    if (tid >= 512) return;    // no barriers below

    const int row = tid >> 3;        // 0..63
    const int cg  = tid & 7;
    const int rw  = (tid >> 3) & 7;  // row-group within wave
    const int rowg2 = blockIdx.x*64 + row;

    const float lat0=latb[row*8+0], lat1=latb[row*8+1], lat2=latb[row*8+2];
    const float lat3=latb[row*8+3], lat4=latb[row*8+4], lat5=latb[row*8+5];
    const float x3 = latb[row*8+6];

    float rr   = 4e-8f * __expf(lat0);
    float epsv = rcpf(1.0f + __expf(-lat1));
    float Kdl  = __expf(lat2);
    float Deff = 1.91e-9f * epsv * sqrtf(epsv);
    float Kgdl = Kdl * Deff * rcpf(rr);
    float S    = rcpf(Kgdl) + fabsf(x3) * rcpf((1.0f - epsv) * Deff);
    float il0  = S * (float)(1.0 / (2.0  * 96485.33 * 34.0));
    float il1  = S * (float)(1.0 / (12.0 * 96485.33 * 34.0));

    float t0s = 2.0f*lat3, t1s = 2.0f*lat4, t2s = 2.0f*lat5;
    float mx = fmaxf(t0s, fmaxf(t1s, t2s));
    float e0 = __expf(t0s-mx), e1 = __expf(t1s-mx), e2 = __expf(t2s-mx);
    float se = e0 + e1 + e2;
    float it0 = se*rcpf(e0), it1 = se*rcpf(e1), it2 = se*rcpf(e2);

    auto itot = [&](int v) -> float {
        f32x4 tb = *(const f32x4*)&tab4[v*4];
        return rcpf(fmaf(tb.x, it0, il0)) + rcpf(fmaf(tb.y, it1, il1)) + rcpf(tb.z*it2);
    };

    // i_tot strictly decreasing in v (2%/step >> float noise).
    bool le0f = itot(0)   <= 200.0f;
    bool le9f = itot(999) <= 200.0f;

    int lo = 0, hi = 999;
#pragma unroll 1
    for (int rd = 0; rd < 3; ++rd){
        int L = hi - lo;
        int p = lo + (L*(cg+1))/9;
        bool le = itot(p) <= 200.0f;
        unsigned long long bal = __ballot(le);
        unsigned m8 = (unsigned)((bal >> (8*rw)) & 0xFFull);
        int tz  = (m8 == 0u) ? 8 : (int)__builtin_ctz(m8);
        int nlo = (tz > 0) ? lo + (L*tz)/9 : lo;
        int nhi = (tz < 8) ? lo + (L*(tz+1))/9 : hi;
        lo = nlo; hi = nhi;
    }
    // interval now <= 2 wide; one unconditional bisect step (no-op at width 1)
    {
        int mid = lo + ((hi-lo)>>1);
        bool lem = itot(mid) <= 200.0f;
        hi = lem ? mid : hi;
        lo = lem ? lo  : mid;
    }
    float da = itot(lo) - 200.0f;   // > 0 under invariant
    float db = 200.0f - itot(hi);   // >= 0
    int idx = (da <= db) ? lo : hi; // tie -> earlier index (argmin-first)
    if (!le9f) idx = 999;
    if (le0f)  idx = 0;

    f32x4 tb = *(const f32x4*)&tab4[idx*4];
    float s0 = rcpf(fmaf(tb.x, it0, il0));
    float s1 = rcpf(fmaf(tb.y, it1, il1));
    float s2 = rcpf(tb.z*it2);
    float inv = rcpf(s0 + s1 + s2);

    if (cg == 0 && rowg2 < nrows){
        float2 o; o.x = s1*inv; o.y = s0*inv;
        reinterpret_cast<float2*>(out)[rowg2] = o;
    }
}

extern "C" void kernel_launch(void* const* d_in, const int* in_sizes, int n_in,
                              void* d_out, int out_size, void* d_ws, size_t ws_size,
                              hipStream_t stream) {
    (void)n_in; (void)d_ws; (void)ws_size; (void)out_size;
    int nrows = in_sizes[0] / 5;
    int nblk = (nrows + 63) / 64;
    phys12<<<dim3(nblk), dim3(1024), 0, stream>>>(
        (const float*)d_in[0],
        (const float*)d_in[1], (const float*)d_in[2],
        (const float*)d_in[3], (const float*)d_in[4],
        (const float*)d_in[5], (const float*)d_in[6],
        (const float*)d_in[7], (const float*)d_in[8],
        (const float*)d_in[9], (const float*)d_in[10],
        (float*)d_out, nrows);
}

// Round 15
// 18.181 us; speedup vs baseline: 1.3231x; 1.0710x over previous
//
#include <hip/hip_runtime.h>
#include <math.h>

typedef __attribute__((ext_vector_type(4))) float f32x4;

__device__ __forceinline__ float rcpf(float x){ return __builtin_amdgcn_rcpf(x); }

// [row][slot] LDS tile in f32x4 units; involution slot ^= (row&7)
__device__ __forceinline__ int slotaddr(int r, int s){ return r*16 + (s ^ (r & 7)); }

__global__ __launch_bounds__(1024, 4) void phys13(
    const float* __restrict__ x,
    const float* __restrict__ W1, const float* __restrict__ b1,
    const float* __restrict__ W2, const float* __restrict__ b2,
    const float* __restrict__ W3, const float* __restrict__ b3,
    const float* __restrict__ W4, const float* __restrict__ b4,
    const float* __restrict__ i0p, const float* __restrict__ alphap,
    float* __restrict__ out, int nrows)
{
    __shared__ __align__(16) f32x4 hb[64*16];    // swizzled [row][slot], 16 KB
    __shared__ __align__(16) float tab4[4000];   // [v][4] invbase per species
    __shared__ float latb[64*8];                 // [row][lat0..5 -> consts, x3]

    const int tid  = threadIdx.x;
    const int lane = tid & 63;                                  // row within block
    const int wvu  = __builtin_amdgcn_readfirstlane(tid >> 6);  // wave 0..15 (uniform)
    const int c0u  = 4*wvu;                                     // 4-col slice base

    // ---------------- prologue: voltage table ----------------
    {
        const float KFRT = (float)(96485.33/(8.314*298.15));
        const float dV = 1.25f/999.0f;
        float a0=alphap[0], a1=alphap[1], a2=alphap[2];
        float i00=i0p[0], i01=i0p[1], i02=i0p[2];
        for (int v = tid; v < 1000; v += 1024){
            float Vv = -1.25f + (float)v*dV;
            tab4[v*4+0] = expf(a0*KFRT*(Vv+0.11f))/i00;
            tab4[v*4+1] = expf(a1*KFRT*(Vv-0.08f))/i01;
            tab4[v*4+2] = expf(a2*KFRT*(Vv))/i02;
            tab4[v*4+3] = 0.f;
        }
    }

    // ---------------- MLP phase: lane = row, wave = 4-col slice ----------------
    const int rowg = blockIdx.x*64 + lane;
    const int rowc = min(rowg, nrows-1);
    float xv[5];
#pragma unroll
    for (int i=0;i<5;i++) xv[i] = x[rowc*5+i];
    if (wvu == 6) latb[lane*8+6] = xv[3];       // stash x3

    // L1: exact nested-fmaf order (validated); weights via scalar path
    float hs[4];
#pragma unroll
    for (int j=0;j<4;j++){
        int c = c0u + j;
        float hv = b1[c];
        hv = fmaf(xv[0], W1[0*64+c], hv);
        hv = fmaf(xv[1], W1[1*64+c], hv);
        hv = fmaf(xv[2], W1[2*64+c], hv);
        hv = fmaf(xv[3], W1[3*64+c], hv);
        hv = fmaf(xv[4], W1[4*64+c], hv);
        hs[j] = fmaxf(hv, 0.f);
    }

#define PUBLISH()                                                         \
    {                                                                     \
        f32x4 t; t.x=hs[0]; t.y=hs[1]; t.z=hs[2]; t.w=hs[3];              \
        hb[slotaddr(lane, wvu)] = t;                                      \
    }

    // 64->64 layer: in-loop b128 consume (one temp, immediately used),
    // A[k&3] rotation with k=4q+e ascending — R7-validated order.
#define BIGLAYER(W, B)                                                    \
    {                                                                     \
        float A[4][4];                                                    \
        _Pragma("unroll")                                                 \
        for (int j=0;j<4;j++){ A[0][j]=(B)[c0u+j]; A[1][j]=0.f; A[2][j]=0.f; A[3][j]=0.f; } \
        _Pragma("unroll")                                                 \
        for (int q=0;q<16;q++){                                           \
            f32x4 t = hb[slotaddr(lane, q)];                              \
            _Pragma("unroll")                                             \
            for (int e=0;e<4;e++){                                        \
                const int k = 4*q + e;                                    \
                A[e][0] = fmaf(t[e], (W)[k*64 + c0u + 0], A[e][0]);       \
                A[e][1] = fmaf(t[e], (W)[k*64 + c0u + 1], A[e][1]);       \
                A[e][2] = fmaf(t[e], (W)[k*64 + c0u + 2], A[e][2]);       \
                A[e][3] = fmaf(t[e], (W)[k*64 + c0u + 3], A[e][3]);       \
            }                                                             \
        }                                                                 \
        _Pragma("unroll")                                                 \
        for (int j=0;j<4;j++) hs[j] = fmaxf((A[0][j]+A[1][j])+(A[2][j]+A[3][j]), 0.f); \
    }

    PUBLISH();                 // h1
    __syncthreads();
    BIGLAYER(W2, b2);
    __syncthreads();           // all waves done reading h1
    PUBLISH();                 // h2
    __syncthreads();
    BIGLAYER(W3, b3);
    __syncthreads();           // all waves done reading h2
    PUBLISH();                 // h3
    __syncthreads();

    // L4: waves 0..5, col = wvu; serial chain (bias first, k ascending — validated)
    if (wvu < 6){
        float a = b4[wvu];
#pragma unroll
        for (int q=0;q<16;q++){
            f32x4 t = hb[slotaddr(lane, q)];
#pragma unroll
            for (int e=0;e<4;e++)
                a = fmaf(t[e], W4[(4*q+e)*6 + wvu], a);
        }
        latb[lane*8+wvu] = a;
    }
    __syncthreads();

    // ---------------- per-row epilogue constants: wave 0 only ----------------
    if (tid < 64){
        const int row = tid;
        float lat0=latb[row*8+0], lat1=latb[row*8+1], lat2=latb[row*8+2];
        float lat3=latb[row*8+3], lat4=latb[row*8+4], lat5=latb[row*8+5];
        float x3 = latb[row*8+6];

        float rr   = 4e-8f * __expf(lat0);
        float epsv = rcpf(1.0f + __expf(-lat1));
        float Kdl  = __expf(lat2);
        float Deff = 1.91e-9f * epsv * sqrtf(epsv);
        float Kgdl = Kdl * Deff * rcpf(rr);
        float S    = rcpf(Kgdl) + fabsf(x3) * rcpf((1.0f - epsv) * Deff);
        float il0  = S * (float)(1.0 / (2.0  * 96485.33 * 34.0));
        float il1  = S * (float)(1.0 / (12.0 * 96485.33 * 34.0));

        float t0s = 2.0f*lat3, t1s = 2.0f*lat4, t2s = 2.0f*lat5;
        float mx = fmaxf(t0s, fmaxf(t1s, t2s));
        float e0 = __expf(t0s-mx), e1 = __expf(t1s-mx), e2 = __expf(t2s-mx);
        float se = e0 + e1 + e2;
        latb[row*8+0] = se*rcpf(e0);   // it0
        latb[row*8+1] = se*rcpf(e1);   // it1
        latb[row*8+2] = se*rcpf(e2);   // it2
        latb[row*8+3] = il0;
        latb[row*8+4] = il1;
    }
    __syncthreads();

    // ---------------- search phase: 8 threads per row (waves 0..7) ----------------
    if (tid >= 512) return;    // no barriers below

    const int row = tid >> 3;        // 0..63
    const int cg  = tid & 7;
    const int rw  = (tid >> 3) & 7;  // row-group within wave
    const int rowg2 = blockIdx.x*64 + row;

    const float it0 = latb[row*8+0], it1 = latb[row*8+1], it2 = latb[row*8+2];
    const float il0 = latb[row*8+3], il1 = latb[row*8+4];

    auto itot = [&](int v) -> float {
        f32x4 tb = *(const f32x4*)&tab4[v*4];
        return rcpf(fmaf(tb.x, it0, il0)) + rcpf(fmaf(tb.y, it1, il1)) + rcpf(tb.z*it2);
    };

    // i_tot strictly decreasing in v (2%/step >> float noise).
    bool le0f = itot(0)   <= 200.0f;
    bool le9f = itot(999) <= 200.0f;

    int lo = 0, hi = 999;
#pragma unroll 1
    for (int rd = 0; rd < 3; ++rd){
        int L = hi - lo;
        int p = lo + (L*(cg+1))/9;
        bool le = itot(p) <= 200.0f;
        unsigned long long bal = __ballot(le);
        unsigned m8 = (unsigned)((bal >> (8*rw)) & 0xFFull);
        int tz  = (m8 == 0u) ? 8 : (int)__builtin_ctz(m8);
        int nlo = (tz > 0) ? lo + (L*tz)/9 : lo;
        int nhi = (tz < 8) ? lo + (L*(tz+1))/9 : hi;
        lo = nlo; hi = nhi;
    }
    // interval now <= 2 wide; one unconditional bisect step (no-op at width 1)
    {
        int mid = lo + ((hi-lo)>>1);
        bool lem = itot(mid) <= 200.0f;
        hi = lem ? mid : hi;
        lo = lem ? lo  : mid;
    }
    float da = itot(lo) - 200.0f;   // > 0 under invariant
    float db = 200.0f - itot(hi);   // >= 0
    int idx = (da <= db) ? lo : hi; // tie -> earlier index (argmin-first)
    if (!le9f) idx = 999;
    if (le0f)  idx = 0;

    f32x4 tb = *(const f32x4*)&tab4[idx*4];
    float s0 = rcpf(fmaf(tb.x, it0, il0));
    float s1 = rcpf(fmaf(tb.y, it1, il1));
    float s2 = rcpf(tb.z*it2);
    float inv = rcpf(s0 + s1 + s2);

    if (cg == 0 && rowg2 < nrows){
        float2 o; o.x = s1*inv; o.y = s0*inv;
        reinterpret_cast<float2*>(out)[rowg2] = o;
    }
}

extern "C" void kernel_launch(void* const* d_in, const int* in_sizes, int n_in,
                              void* d_out, int out_size, void* d_ws, size_t ws_size,
                              hipStream_t stream) {
    (void)n_in; (void)d_ws; (void)ws_size; (void)out_size;
    int nrows = in_sizes[0] / 5;
    int nblk = (nrows + 63) / 64;
    phys13<<<dim3(nblk), dim3(1024), 0, stream>>>(
        (const float*)d_in[0],
        (const float*)d_in[1], (const float*)d_in[2],
        (const float*)d_in[3], (const float*)d_in[4],
        (const float*)d_in[5], (const float*)d_in[6],
        (const float*)d_in[7], (const float*)d_in[8],
        (const float*)d_in[9], (const float*)d_in[10],
        (float*)d_out, nrows);
}

// Round 18
// 14.146 us; speedup vs baseline: 1.7005x; 1.2852x over previous
//
#include <hip/hip_runtime.h>
#include <math.h>

typedef __attribute__((ext_vector_type(4))) float f32x4;

__device__ __forceinline__ float rcpf(float x){ return __builtin_amdgcn_rcpf(x); }

__global__ __launch_bounds__(1024, 4) void phys16(
    const float* __restrict__ x,
    const float* __restrict__ W1, const float* __restrict__ b1,
    const float* __restrict__ W2, const float* __restrict__ b2,
    const float* __restrict__ W3, const float* __restrict__ b3,
    const float* __restrict__ W4, const float* __restrict__ b4,
    const float* __restrict__ i0p, const float* __restrict__ alphap,
    float* __restrict__ out, int nrows)
{
    __shared__ float hbA[64*64];                // [k][row] layer-exchange buffer A
    __shared__ float hbB[64*64];                // [k][row] layer-exchange buffer B
    __shared__ __align__(16) float tab4[4000];  // [v][4] invbase per species
    __shared__ float latb[64*8];                // [row][lat->consts, x3]

    const int tid  = threadIdx.x;
    const int lane = tid & 63;                                  // row within block
    const int wvu  = __builtin_amdgcn_readfirstlane(tid >> 6);  // wave 0..15 (uniform)
    const int c0u  = 4*wvu;                                     // 4-col slice base

    // ---------------- prologue: voltage table ----------------
    {
        const float KFRT = (float)(96485.33/(8.314*298.15));
        const float dV = 1.25f/999.0f;
        float a0=alphap[0], a1=alphap[1], a2=alphap[2];
        float i00=i0p[0], i01=i0p[1], i02=i0p[2];
        for (int v = tid; v < 1000; v += 1024){
            float Vv = -1.25f + (float)v*dV;
            tab4[v*4+0] = expf(a0*KFRT*(Vv+0.11f))/i00;
            tab4[v*4+1] = expf(a1*KFRT*(Vv-0.08f))/i01;
            tab4[v*4+2] = expf(a2*KFRT*(Vv))/i02;
            tab4[v*4+3] = 0.f;
        }
    }

    // ---------------- MLP phase: lane = row, wave = 4-col slice ----------------
    const int rowg = blockIdx.x*64 + lane;
    const int rowc = min(rowg, nrows-1);
    float xv[5];
#pragma unroll
    for (int i=0;i<5;i++) xv[i] = x[rowc*5+i];
    if (wvu == 6) latb[lane*8+6] = xv[3];       // stash x3

    // L1: exact nested-fmaf order (validated); weights via scalar path
    float hs[4];
#pragma unroll
    for (int j=0;j<4;j++){
        int c = c0u + j;
        float hv = b1[c];
        hv = fmaf(xv[0], W1[0*64+c], hv);
        hv = fmaf(xv[1], W1[1*64+c], hv);
        hv = fmaf(xv[2], W1[2*64+c], hv);
        hv = fmaf(xv[3], W1[3*64+c], hv);
        hv = fmaf(xv[4], W1[4*64+c], hv);
        hs[j] = fmaxf(hv, 0.f);
    }

#define PUBLISH(BUF)                                                      \
    {                                                                     \
        _Pragma("unroll")                                                 \
        for (int j=0;j<4;j++) BUF[(c0u+j)*64 + lane] = hs[j];             \
    }

    // 64->64 layer: R7-exact — h per-k from LDS (coalesced b32, in-loop),
    // weights wave-uniform scalar loads, A[k&3] rotation, k ascending.
#define BIGLAYER(BUF, W, B)                                               \
    {                                                                     \
        float A[4][4];                                                    \
        _Pragma("unroll")                                                 \
        for (int j=0;j<4;j++){ A[0][j]=(B)[c0u+j]; A[1][j]=0.f; A[2][j]=0.f; A[3][j]=0.f; } \
        _Pragma("unroll 16")                                              \
        for (int k=0;k<64;k++){                                           \
            float hk = BUF[k*64 + lane];                                  \
            _Pragma("unroll")                                             \
            for (int j=0;j<4;j++)                                         \
                A[k&3][j] = fmaf(hk, (W)[k*64 + c0u + j], A[k&3][j]);     \
        }                                                                 \
        _Pragma("unroll")                                                 \
        for (int j=0;j<4;j++) hs[j] = fmaxf((A[0][j]+A[1][j])+(A[2][j]+A[3][j]), 0.f); \
    }

    PUBLISH(hbA);              // h1 -> A
    __syncthreads();
    BIGLAYER(hbA, W2, b2);     // L2 reads A ...
    PUBLISH(hbB);              // ... h2 -> B (no conflict with A reads)
    __syncthreads();
    BIGLAYER(hbB, W3, b3);     // L3 reads B ...
    PUBLISH(hbA);              // ... h3 -> A (A reads all ended at prior barrier)
    __syncthreads();

    // L4: waves 0..5, col = wvu; serial chain (bias first, k ascending — validated)
    if (wvu < 6){
        float a = b4[wvu];
#pragma unroll
        for (int k=0;k<64;k++)
            a = fmaf(hbA[k*64 + lane], W4[k*6 + wvu], a);
        latb[lane*8+wvu] = a;
    }
    __syncthreads();

    // ---------------- per-row epilogue constants: wave 0 only (validated R13/15) ----------------
    if (tid < 64){
        const int row = tid;
        float lat0=latb[row*8+0], lat1=latb[row*8+1], lat2=latb[row*8+2];
        float lat3=latb[row*8+3], lat4=latb[row*8+4], lat5=latb[row*8+5];
        float x3 = latb[row*8+6];

        float rr   = 4e-8f * __expf(lat0);
        float epsv = rcpf(1.0f + __expf(-lat1));
        float Kdl  = __expf(lat2);
        float Deff = 1.91e-9f * epsv * sqrtf(epsv);
        float Kgdl = Kdl * Deff * rcpf(rr);
        float S    = rcpf(Kgdl) + fabsf(x3) * rcpf((1.0f - epsv) * Deff);
        float il0  = S * (float)(1.0 / (2.0  * 96485.33 * 34.0));
        float il1  = S * (float)(1.0 / (12.0 * 96485.33 * 34.0));

        float t0s = 2.0f*lat3, t1s = 2.0f*lat4, t2s = 2.0f*lat5;
        float mx = fmaxf(t0s, fmaxf(t1s, t2s));
        float e0 = __expf(t0s-mx), e1 = __expf(t1s-mx), e2 = __expf(t2s-mx);
        float se = e0 + e1 + e2;
        latb[row*8+0] = se*rcpf(e0);   // it0
        latb[row*8+1] = se*rcpf(e1);   // it1
        latb[row*8+2] = se*rcpf(e2);   // it2
        latb[row*8+3] = il0;
        latb[row*8+4] = il1;
    }
    __syncthreads();

    // ---------------- search phase: 8 threads per row (waves 0..7) ----------------
    if (tid >= 512) return;    // no barriers below

    const int row = tid >> 3;        // 0..63
    const int cg  = tid & 7;
    const int rw  = (tid >> 3) & 7;  // row-group within wave
    const int rowg2 = blockIdx.x*64 + row;

    const float it0 = latb[row*8+0], it1 = latb[row*8+1], it2 = latb[row*8+2];
    const float il0 = latb[row*8+3], il1 = latb[row*8+4];

    auto itot = [&](int v) -> float {
        f32x4 tb = *(const f32x4*)&tab4[v*4];
        return rcpf(fmaf(tb.x, it0, il0)) + rcpf(fmaf(tb.y, it1, il1)) + rcpf(tb.z*it2);
    };

    // i_tot strictly decreasing in v (2%/step >> float noise).
    bool le0f = itot(0)   <= 200.0f;
    bool le9f = itot(999) <= 200.0f;

    int lo = 0, hi = 999;
#pragma unroll 1
    for (int rd = 0; rd < 3; ++rd){
        int L = hi - lo;
        int p = lo + (L*(cg+1))/9;
        bool le = itot(p) <= 200.0f;
        unsigned long long bal = __ballot(le);
        unsigned m8 = (unsigned)((bal >> (8*rw)) & 0xFFull);
        int tz  = (m8 == 0u) ? 8 : (int)__builtin_ctz(m8);
        int nlo = (tz > 0) ? lo + (L*tz)/9 : lo;
        int nhi = (tz < 8) ? lo + (L*(tz+1))/9 : hi;
        lo = nlo; hi = nhi;
    }
    // interval now <= 2 wide; one unconditional bisect step (no-op at width 1)
    {
        int mid = lo + ((hi-lo)>>1);
        bool lem = itot(mid) <= 200.0f;
        hi = lem ? mid : hi;
        lo = lem ? lo  : mid;
    }
    float da = itot(lo) - 200.0f;   // > 0 under invariant
    float db = 200.0f - itot(hi);   // >= 0
    int idx = (da <= db) ? lo : hi; // tie -> earlier index (argmin-first)
    if (!le9f) idx = 999;
    if (le0f)  idx = 0;

    f32x4 tb = *(const f32x4*)&tab4[idx*4];
    float s0 = rcpf(fmaf(tb.x, it0, il0));
    float s1 = rcpf(fmaf(tb.y, it1, il1));
    float s2 = rcpf(tb.z*it2);
    float inv = rcpf(s0 + s1 + s2);

    if (cg == 0 && rowg2 < nrows){
        float2 o; o.x = s1*inv; o.y = s0*inv;
        reinterpret_cast<float2*>(out)[rowg2] = o;
    }
}

extern "C" void kernel_launch(void* const* d_in, const int* in_sizes, int n_in,
                              void* d_out, int out_size, void* d_ws, size_t ws_size,
                              hipStream_t stream) {
    (void)n_in; (void)d_ws; (void)ws_size; (void)out_size;
    int nrows = in_sizes[0] / 5;
    int nblk = (nrows + 63) / 64;
    phys16<<<dim3(nblk), dim3(1024), 0, stream>>>(
        (const float*)d_in[0],
        (const float*)d_in[1], (const float*)d_in[2],
        (const float*)d_in[3], (const float*)d_in[4],
        (const float*)d_in[5], (const float*)d_in[6],
        (const float*)d_in[7], (const float*)d_in[8],
        (const float*)d_in[9], (const float*)d_in[10],
        (float*)d_out, nrows);
}